// Round 9
// baseline (109.925 us; speedup 1.0000x reference)
//
#include <hip/hip_runtime.h>
#include <stdint.h>

// HamiltonianFlow: x [256, 8, 32, 2] (q,p); H = 0.5*sum(p^2) + MLP(q).
// dq/dt = p, dp/dt = -W u(z), z = W^T q + b1, u = (1-tanh^2(z)).*W2.
// z-space iteration with M = W^T W (R15-R23 verified).
//
// R31 = R30's exchange loop + ONE-TIME SETUP KERNEL. R30 falsified the
// conflict theory (swizzle changed SQ_LDS_BANK_CONFLICT by exactly 0 ->
// conflicts live in setup, not the loop; dur unchanged). What remains
// large and removable: the setup phase (wldsT staging + M-build: 2048
// ds_read_b128/CU ~ 24.6k LDS cyc + 128 MFMA/wave + mscr round-trips +
// 32 lgkmcnt(0) serializations ~ 12-15us) is REDUNDANTLY recomputed by
// all 256 blocks, but M and W^T are block-invariant. Hoist them into a
// tiny setup kernel writing d_ws:
//   Wt_f16[c][r] = (f16)W1[r][c]          (131072 B)
//   Mf16[c][k]   = M[k][c], M = Wf16^T Wf16, f32 accum  (131072 B)
// (M symmetric: block b computes row M[b][.] and stores it coalesced at
//  Mf[b*256+t], which by symmetry is the [c][k] layout.)
// Main kernel: wF0/wM0 loaded as contiguous b128 from L2-hot global;
// wldsT/mscr/staging/M-build DELETED; LDS = ubuf only (17408 B);
// epilogue wBt from W1 f32 (R29c-verified identical-conversion path).
// Setup numerics: same f16-rounded W inputs, exact f16xf16 products,
// f32 accumulation; only summation order differs from the MFMA build ->
// same rounding class as the f16-rounded M itself (verified tolerant).
// Requires ws_size >= 262144 B.
//
// Exchange loop (byte-for-byte R30 = best measured structure, 46.3-47us):
// 16 waves x 1 tile (1024 thr), 4-step exchange, rows 4*step+stage hold
// u-vectors, ONE barrier + ONE 8-MFMA block per 4 steps; quad q owns
// step q via horizon-4 proxy predictor {SBp,SVp} (lag-1 exchange, err
// ~1e-5 stage-z, >=2 orders under the f16 u-rounding floor); exact
// 4-step advance: z += 4dt*P - dtdt6*SV; P -= dt6*SB;
// SB = bfly4(B), SV = bfly4((3-q)B + A), A=Y1+Y2+Y3, B=Y1+2Y2+2Y3+Y4.
// permlane bfly4; exp-fold (2z chain) + rcp; R30 write/read swizzle.
// FULL unroll on every reg-array access (R4: dynamic index => scratch).
// Numerics: f16 storage (W, M, u, S), fp32 MFMA accum + fp32 z/P state.

typedef _Float16 v8h __attribute__((ext_vector_type(8)));
typedef float v4f __attribute__((ext_vector_type(4)));

#define NSTEPS 100
#define NEX 25    // 4 RK4 steps per exchange
#define US 272    // ubuf row stride, f16 (544 B == 32 mod 128)

// D(+=C) in VGPRs, A (packed-vector frag) in VGPRs, B (M-frag) from AGPRs.
#define MFMA_AV(C, A, B) \
    asm("v_mfma_f32_16x16x32_f16 %0, %1, %2, %0" : "+v"(C) : "v"(A), "a"(B))

// 4-group butterfly sum over lanes {l, l^16, l^32, l^48}, pure VALU.
__device__ __forceinline__ float bfly4(float x) {
    float a = x, b = x;
    asm("v_permlane16_swap_b32 %0, %1" : "+v"(a), "+v"(b));
    float s = a + b;
    float c = s, d = s;
    asm("v_permlane32_swap_b32 %0, %1" : "+v"(c), "+v"(d));
    return c + d;
}

// u/(4*w2) eval on pre-doubled arg zz = 2*z:  r = rcp(e^zz + 1);
// u = 4*w2*(r - r^2)  ==  (1 - tanh^2(z)) * w2  exactly in algebra.
__device__ __forceinline__ float ueval2(float zz, float w4) {
    float e_ = __expf(zz);
    float r_ = __builtin_amdgcn_rcpf(e_ + 1.f);   // vs IEEE div: ~1e-7 rel
    return w4 * __builtin_fmaf(-r_, r_, r_);
}

// ---- one-time setup: Wt_f16 (W^T) and Mf16 = (Wf16^T Wf16) as [c][k] ----
__global__ __launch_bounds__(256)
void ham_setup(const float* __restrict__ W1, _Float16* __restrict__ wt,
               _Float16* __restrict__ mf)
{
    const int b = blockIdx.x;    // 0..255
    const int t = threadIdx.x;   // 0..255
    // Wt[c=b][r=t] = (f16)W[t][b]   (scalar, L2-resident, one per thread)
    wt[b * 256 + t] = (_Float16)W1[t * 256 + b];
    // M[b][t] = sum_r f16(W[r][b]) * f16(W[r][t]), f32 accum.
    float acc = 0.f;
    #pragma unroll 4
    for (int r = 0; r < 256; ++r) {
        float wk = (float)(_Float16)W1[r * 256 + b];   // broadcast per wave
        float wc = (float)(_Float16)W1[r * 256 + t];   // coalesced
        acc = __builtin_fmaf(wk, wc, acc);
    }
    // store coalesced; by symmetry Mf[b*256+t] = M[t][b] = M[b][t] = acc
    mf[b * 256 + t] = (_Float16)acc;
}

__global__ __launch_bounds__(1024, 4)
void ham_kernel(const float* __restrict__ x0, const float* __restrict__ W1,
                const float* __restrict__ b1, const float* __restrict__ W2,
                const _Float16* __restrict__ wt, const _Float16* __restrict__ mf,
                float* __restrict__ out)
{
    __shared__ __align__(128) _Float16 ubuf[2 * 16 * US];   // 17408 B only

    const int t = threadIdx.x;
    const int w = t >> 6;          // wave 0..15: owns tile w (16 comps)
    const int l = t & 63;
    const int quad = l >> 4;       // step-within-exchange owned by this lane
    const int s = l & 15;          // owned column / A-row
    const int c0 = 16 * w + s;     // owned component
    const int blk = blockIdx.x;
    const int kq = 8 * quad;
    const int sel = (s & 3) * US;  // prologue/epilogue A-row select (rows 0-3)

    // ---- frags from precomputed global (L2-hot): contiguous b128 ----
    v8h wF0[8], wM0[8];
    #pragma unroll
    for (int kk = 0; kk < 8; ++kk) {
        wF0[kk] = *(const v8h*)(wt + c0 * 256 + 32 * kk + kq);
        wM0[kk] = *(const v8h*)(mf + c0 * 256 + 32 * kk + kq);
    }

    const float b1r0 = b1[c0];
    const float w4 = 4.f * W2[c0];
    float2 qp0 = ((const float2*)(x0 + (size_t)blk * 512))[c0];
    const float q0o0 = qp0.x, p0o0 = qp0.y;

    // ---- prologue: buf0 rows {q0, p0, 0, 0} -> z1 (C[0]), P (C[1]) ----
    if (quad == 0) {
        ubuf[c0] = (_Float16)q0o0;
        ubuf[US + c0] = (_Float16)p0o0;
        ubuf[2 * US + c0] = (_Float16)0.f;
        ubuf[3 * US + c0] = (_Float16)0.f;
    }
    __syncthreads();
    float z1, P;
    {
        const _Float16* ab = ubuf + sel + 8 * quad;
        v4f C0a = {0.f,0.f,0.f,0.f}, C0b = {0.f,0.f,0.f,0.f};
        #pragma unroll
        for (int kk = 0; kk < 8; kk += 2) {
            v8h a0 = *(const v8h*)(ab + 32 * kk);
            v8h a1 = *(const v8h*)(ab + 32 * (kk + 1));
            C0a = __builtin_amdgcn_mfma_f32_16x16x32_f16(a0, wF0[kk], C0a, 0, 0, 0);
            C0b = __builtin_amdgcn_mfma_f32_16x16x32_f16(a1, wF0[kk + 1], C0b, 0, 0, 0);
        }
        v4f C0s = C0a + C0b;
        z1 = C0s[0] + b1r0;  P = C0s[1];
    }
    __syncthreads();   // prologue reads done before u(0) overwrites buf0

    const float dt = 0.01f, hdt = 0.005f, dt6 = 0.01f / 6.f;
    const float dtdt6 = dt * dt6, hdt2 = hdt * hdt, dthdt = dt * hdt;
    const float fourdt = 4.f * dt;
    // per-quad (step j = quad) prediction coefs in {SBp, SVp} form
    // (R27-verified): Pp = P - (j/4)dt6*SBp;
    //   zp2 = 2z + 2j*dt*P + [j(4-j)dtdt6/4]*SBp - [j*dtdt6/2]*SVp
    const float qf  = (float)quad;
    const float cPn   = -(qf * 0.25f * dt6);
    const float K2cz1 = 2.f * qf * dt;
    const float K2B   = qf * (4.f - qf) * dtdt6 * 0.25f;
    const float K2Vn  = -(qf * dtdt6 * 0.5f);
    const float K2hdt = 2.f * hdt;
    const float K2hdt2n = -2.f * hdt2;
    const float K2dt  = 2.f * dt;
    const float K2dthdtn = -2.f * dthdt;
    const float wB  = 3.f - qf;          // SWB weight (3-j)

    // ---- ubuf addressing (R30 swizzle, HW-verified) ----
    const int cw = c0 ^ (quad << 3);
    const int R0 = 4 * quad;
    const int wo0 = (R0 + 0) * US + cw;
    const int wo1 = (R0 + 1) * US + (cw ^ 32);
    const int wo2 = (R0 + 2) * US + cw;
    const int wo3 = (R0 + 3) * US + (cw ^ 32);
    const int sx = (s >> 2) & 3;
    const int rbase = s * US + 8 * (quad ^ sx);
    const int sodd = (s & 1) << 5;
    const _Float16* pe = ubuf + rbase + sodd;          // logical even kk
    const _Float16* po = ubuf + rbase + 32 - sodd;     // logical odd  kk

    // lag state (previous exchange's sums / own-step Ys; exchange 0: zeros
    // -> benign one-time transient, R25/R27-verified class)
    float SBp = 0.f, SVp = 0.f;
    float Y1L = 0.f, Y2L = 0.f;
    float S1p = 0.f, S23p = 0.f;
    float cn = 99.f - qf;

    #pragma unroll 1
    for (int e = 0; e < NEX; ++e) {
        const int bo = (e & 1) * (16 * US);   // double-buffer offset

        // ---- predicted state for own step; 4 stage 2z's; 4 u evals ----
        float Pp  = __builtin_fmaf(cPn, SBp, P);
        float zp2 = __builtin_fmaf(K2cz1, P, z1 + z1);
        zp2 = __builtin_fmaf(K2B, SBp, zp2);
        zp2 = __builtin_fmaf(K2Vn, SVp, zp2);
        float zb2 = __builtin_fmaf(K2hdt, Pp, zp2);
        float zc2 = __builtin_fmaf(K2hdt2n, Y1L, zb2);
        float zd2 = __builtin_fmaf(K2dt, Pp, zp2);
        zd2 = __builtin_fmaf(K2dthdtn, Y2L, zd2);

        float ua = ueval2(zp2, w4);
        float ub = ueval2(zb2, w4);
        float uc = ueval2(zc2, w4);
        float ud = ueval2(zd2, w4);

        ubuf[bo + wo0] = (_Float16)ua;
        ubuf[bo + wo1] = (_Float16)ub;
        ubuf[bo + wo2] = (_Float16)uc;
        ubuf[bo + wo3] = (_Float16)ud;
        __syncthreads();   // the ONLY barrier per exchange (4 steps)

        // ---- ONE MFMA block: step-q Y1..Y4 for own comp, in-lane ----
        v4f C0s;
        {
            v4f C0a = {0.f,0.f,0.f,0.f}, C0b = {0.f,0.f,0.f,0.f};
            #pragma unroll
            for (int kk = 0; kk < 8; kk += 2) {
                v8h a0 = *(const v8h*)(pe + bo + 32 * kk);
                v8h a1 = *(const v8h*)(po + bo + 32 * kk);
                MFMA_AV(C0a, a0, wM0[kk]);
                MFMA_AV(C0b, a1, wM0[kk + 1]);
            }
            C0s = C0a + C0b;
        }
        // no second barrier: next exchange writes the OTHER buffer (R24).

        // ---- exact 4-step advance via quad-weighted butterfly sums ----
        float Y1 = C0s[0], Y2 = C0s[1], Y3 = C0s[2], Y4 = C0s[3];
        float tA = Y2 + Y3;
        float A  = Y1 + tA;                    // Y1+Y2+Y3
        float B  = A + tA + Y4;                // Y1+2Y2+2Y3+Y4
        float V  = __builtin_fmaf(wB, B, A);   // (3-j)*B + A
        float SB = bfly4(B);
        float SV = bfly4(V);                   // = SWB + SA (exact)

        z1 = __builtin_fmaf(fourdt, P, z1);    // z += 4dt*P (old P)
        z1 = __builtin_fmaf(-dtdt6, SV, z1);   //    - dt*dt6*SWB - dtdt6*SA
        P  = __builtin_fmaf(-dt6, SB, P);      // P -= dt6*SB

        SBp = SB;  SVp = SV;  Y1L = Y1;  Y2L = Y2;   // lag state

        // ---- per-lane S partials: full sp,sq for own step ----
        float tv = ub + uc;
        float sp = __builtin_fmaf(2.f, tv, ua + ud);
        float sq = ua + tv;
        S1p += sp;
        S23p = __builtin_fmaf(cn, sp, S23p) + sq;
        cn -= 4.f;
    }

    // ---- epilogue: B-frag from GLOBAL W1 (contiguous; L2-hot; same
    //      f32->f16 conversion as setup => identical class, R29c path) ----
    v8h wBt0[8];
    #pragma unroll
    for (int kk = 0; kk < 8; ++kk) {
        const float* wp = W1 + c0 * 256 + 32 * kk + kq;
        v4f lo = *(const v4f*)(wp);
        v4f hi = *(const v4f*)(wp + 4);
        v8h h;
        h[0] = (_Float16)lo[0]; h[1] = (_Float16)lo[1];
        h[2] = (_Float16)lo[2]; h[3] = (_Float16)lo[3];
        h[4] = (_Float16)hi[0]; h[5] = (_Float16)hi[1];
        h[6] = (_Float16)hi[2]; h[7] = (_Float16)hi[3];
        wBt0[kk] = h;
    }

    // ---- reduce S over the 4 quads; buf0 rows {S1, S23, 0, 0} ----
    const float S1f  = bfly4(S1p);
    const float S23f = bfly4(S23p);
    __syncthreads();   // last exchange's reads (buf0, e=24) done
    if (quad == 0) {
        ubuf[c0] = (_Float16)S1f;
        ubuf[US + c0] = (_Float16)S23f;
        ubuf[2 * US + c0] = (_Float16)0.f;
        ubuf[3 * US + c0] = (_Float16)0.f;
    }
    __syncthreads();
    float D10, D20;
    {
        const _Float16* ab = ubuf + sel + 8 * quad;
        v4f C0a = {0.f,0.f,0.f,0.f}, C0b = {0.f,0.f,0.f,0.f};
        #pragma unroll
        for (int kk = 0; kk < 8; kk += 2) {
            v8h a0 = *(const v8h*)(ab + 32 * kk);
            v8h a1 = *(const v8h*)(ab + 32 * (kk + 1));
            C0a = __builtin_amdgcn_mfma_f32_16x16x32_f16(a0, wBt0[kk], C0a, 0, 0, 0);
            C0b = __builtin_amdgcn_mfma_f32_16x16x32_f16(a1, wBt0[kk + 1], C0b, 0, 0, 0);
        }
        v4f C0s = C0a + C0b;
        D10 = C0s[0];  D20 = C0s[1];
    }
    const float dt6e = 0.01f / 6.f, dtdt6e = 0.01f * dt6e;
    float pT0 = p0o0 - dt6e * D10;
    float qT0 = q0o0 + 0.01f * (float)NSTEPS * p0o0 - dtdt6e * D20;

    if (quad == 0)
        ((float2*)(out + (size_t)blk * 512))[c0] = make_float2(qT0, pT0);
}

extern "C" void kernel_launch(void* const* d_in, const int* in_sizes, int n_in,
                              void* d_out, int out_size, void* d_ws, size_t ws_size,
                              hipStream_t stream) {
    const float* x0 = (const float*)d_in[0];
    const float* W1 = (const float*)d_in[1];
    const float* b1 = (const float*)d_in[2];
    const float* W2 = (const float*)d_in[3];
    // d_in[4] = b2: constant offset, no effect on the gradient/dynamics.
    float* out = (float*)d_out;
    // workspace: Wt_f16 [256*256] then Mf16 [256*256]  (262144 B total)
    _Float16* wt = (_Float16*)d_ws;
    _Float16* mf = wt + 256 * 256;
    hipLaunchKernelGGL(ham_setup, dim3(256), dim3(256), 0, stream, W1, wt, mf);
    hipLaunchKernelGGL(ham_kernel, dim3(256), dim3(1024), 0, stream,
                       x0, W1, b1, W2, wt, mf, out);
}

// Round 10
// 107.270 us; speedup vs baseline: 1.0247x; 1.0247x over previous
//
#include <hip/hip_runtime.h>
#include <stdint.h>

// HamiltonianFlow: x [256, 8, 32, 2] (q,p); H = 0.5*sum(p^2) + MLP(q).
// dq/dt = p, dp/dt = -W u(z), z = W^T q + b1, u = (1-tanh^2(z)).*W2.
// z-space iteration with M = W^T W (R15-R23 verified).
//
// R32 = R31 precompute + 4-WAVE x 4-TILE restructure. R31 measured the
// exchange loop clean at ~4.0k cyc/exchange; budget: VALU issue ~1540/SIMD
// + LDS-read phase ~1536/CU + MFMA ~540 + latency, SUMMED because 16
// barrier-lockstepped waves storm each pipe in phase. R26 (half LDS,
// same VALU/SIMD) == R27 pins the wall on VALU issue + phase serialization.
// Restructure at constant total work: 256 thr = 4 waves; wave w owns comps
// 64w..64w+63; lane (q,s) owns 4 CONSECUTIVE comps cb+tt, cb = 64w+4s.
// Per exchange per wave: load 8 A-frags ONCE, reuse across 4 B-tiles
// (32 MFMA) -> A-tile ds_reads per CU drop 4x (128 -> 32 b128); barrier
// syncs 4 waves; per-SIMD VALU unchanged but single-stream with 16
// independent exp chains -> ILP hides latency instead of lockstep TLP.
// wM in 128 AGPRs ("a" constraint, unified file); ~290 regs total ->
// __launch_bounds__(256,1), 1 wave/SIMD by design. Spill tripwire:
// WRITE_SIZE (R29b lesson).
//
// u-tile [16 rows][256 comps] f16, 16B-granule XOR swizzle:
//   phys16Bchunk = (comp>>3) ^ (row&7)
// Reads (row s, chunk 4kk|q): addr = s*256 + 8*(q^(s&3)) + 32*(kk^((s>>2)&1))
//   -> per-instr slot = 4*((kk&1)^b) + (q^(s&3)): exactly 8 lanes/slot =
//   conflict-free minimum (verified over q,s,s&8).
// Writes (row R=4q+r, b64 of comps cb..cb+3): slot = (s>>1)^((4q+r)&7):
//   8 lanes x 8B per 16B slot = 4-cyc b64 minimum, conflict-free.
// Prologue/epilogue replicate rows 0-3 (read row s&3): same XOR family.
//
// Exchange semantics = R27 (verified): quad q owns step q; horizon-4
// proxy predictor {SBp,SVp} (lag-1 exchange, err ~1e-5 stage-z, >=2
// orders under f16 u-rounding floor); exact 4-step advance:
//   z += 4dt*P - dtdt6*SV;  P -= dt6*SB
//   SB = bfly4(B), SV = bfly4((3-q)B + A), A=Y1+Y2+Y3, B=Y1+2Y2+2Y3+Y4
// bfly4 sums the 4 quad-copies (permlane, pure VALU). ONE barrier per
// exchange (R24 double-buffer argument). exp-fold (2z chain) + rcp.
// FULL unroll on every reg-array access (R4: dynamic index => scratch).
// Numerics: f16 storage (W, M, u, S), fp32 MFMA accum + fp32 z/P state.
// Setup kernel: LDS-staged column (kills serial uniform-load chain).

typedef _Float16 v8h __attribute__((ext_vector_type(8)));
typedef _Float16 v4h __attribute__((ext_vector_type(4)));
typedef float v4f __attribute__((ext_vector_type(4)));

#define NEX 25    // 4 RK4 steps per exchange

// D(+=C) in VGPRs, A (u-frag) in VGPRs, B (M-frag) from AGPRs.
#define MFMA_AV(C, A, B) \
    asm("v_mfma_f32_16x16x32_f16 %0, %1, %2, %0" : "+v"(C) : "v"(A), "a"(B))

// 4-group butterfly sum over lanes {l, l^16, l^32, l^48}, pure VALU.
__device__ __forceinline__ float bfly4(float x) {
    float a = x, b = x;
    asm("v_permlane16_swap_b32 %0, %1" : "+v"(a), "+v"(b));
    float s = a + b;
    float c = s, d = s;
    asm("v_permlane32_swap_b32 %0, %1" : "+v"(c), "+v"(d));
    return c + d;
}

// u/(4*w2) eval on pre-doubled arg zz = 2*z:  r = rcp(e^zz + 1);
// u = 4*w2*(r - r^2)  ==  (1 - tanh^2(z)) * w2  exactly in algebra.
__device__ __forceinline__ float ueval2(float zz, float w4) {
    float e_ = __expf(zz);
    float r_ = __builtin_amdgcn_rcpf(e_ + 1.f);   // vs IEEE div: ~1e-7 rel
    return w4 * __builtin_fmaf(-r_, r_, r_);
}

// ---- one-time setup: Wt_f16 (W^T) and Mf16 = (Wf16^T Wf16) as [c][k] ----
__global__ __launch_bounds__(256)
void ham_setup(const float* __restrict__ W1, _Float16* __restrict__ wt,
               _Float16* __restrict__ mf)
{
    __shared__ float colb[256];
    const int b = blockIdx.x;    // 0..255
    const int t = threadIdx.x;   // 0..255
    float wv = W1[t * 256 + b];               // W[t][b] (strided, one-time)
    wt[b * 256 + t] = (_Float16)wv;           // Wt[c=b][r=t]
    colb[t] = (float)(_Float16)wv;            // f16-rounded column b in LDS
    __syncthreads();
    float acc = 0.f;
    #pragma unroll 8
    for (int r = 0; r < 256; ++r) {
        float wc = (float)(_Float16)W1[r * 256 + t];   // coalesced, L2-hot
        acc = __builtin_fmaf(colb[r], wc, acc);        // LDS broadcast
    }
    mf[b * 256 + t] = (_Float16)acc;   // M symmetric: [b][t] == [t][b]
}

__global__ __launch_bounds__(256, 1)
void ham_kernel(const float* __restrict__ x0, const float* __restrict__ W1,
                const float* __restrict__ b1, const float* __restrict__ W2,
                const _Float16* __restrict__ wt, const _Float16* __restrict__ mf,
                float* __restrict__ out)
{
    __shared__ __align__(128) _Float16 ubuf[2 * 16 * 256];   // 16384 B

    const int t = threadIdx.x;
    const int w = t >> 6;          // wave 0..3: owns comps 64w..64w+63
    const int l = t & 63;
    const int quad = l >> 4;       // step-within-exchange owned by this lane
    const int s = l & 15;          // A-row / B-col index
    const int blk = blockIdx.x;
    const int kq = 8 * quad;
    const int cb = 64 * w + 4 * s;     // first owned comp (cb..cb+3)
    const int chb = cb >> 3;           // writer 16B-chunk = 8w + (s>>1)
    const int clo = cb & 7;            // = 4*(s&1)

    // ---- wM: 4 tiles x 8 kk B-frags from precomputed M (L2-hot) ----
    v8h wM[4][8];
    #pragma unroll
    for (int tt = 0; tt < 4; ++tt)
        #pragma unroll
        for (int kk = 0; kk < 8; ++kk)
            wM[tt][kk] = *(const v8h*)(mf + (cb + tt) * 256 + 32 * kk + kq);

    float b1r[4], w4v[4];
    #pragma unroll
    for (int tt = 0; tt < 4; ++tt) {
        b1r[tt] = b1[cb + tt];
        w4v[tt] = 4.f * W2[cb + tt];
    }
    v4f qp01 = *(const v4f*)(x0 + (size_t)blk * 512 + 2 * cb);      // q0,p0,q1,p1
    v4f qp23 = *(const v4f*)(x0 + (size_t)blk * 512 + 2 * cb + 4);  // q2,p2,q3,p3
    float q0v[4] = {qp01[0], qp01[2], qp23[0], qp23[2]};
    float p0v[4] = {qp01[1], qp01[3], qp23[1], qp23[3]};

    // ---- prologue: rows {q0,p0,0,0} -> z1 (C[0]), P (C[1]) per tile ----
    if (quad == 0) {
        v4h r0 = {(_Float16)q0v[0], (_Float16)q0v[1],
                  (_Float16)q0v[2], (_Float16)q0v[3]};
        v4h r1 = {(_Float16)p0v[0], (_Float16)p0v[1],
                  (_Float16)p0v[2], (_Float16)p0v[3]};
        v4h rz = {(_Float16)0.f, (_Float16)0.f, (_Float16)0.f, (_Float16)0.f};
        *(v4h*)(ubuf + 0 * 256 + 8 * (chb ^ 0) + clo) = r0;
        *(v4h*)(ubuf + 1 * 256 + 8 * (chb ^ 1) + clo) = r1;
        *(v4h*)(ubuf + 2 * 256 + 8 * (chb ^ 2) + clo) = rz;
        *(v4h*)(ubuf + 3 * 256 + 8 * (chb ^ 3) + clo) = rz;
    }
    __syncthreads();
    float z1[4], P[4];
    {
        const _Float16* ab = ubuf + (s & 3) * 256 + 8 * (quad ^ (s & 3));
        v8h a[8];
        #pragma unroll
        for (int kk = 0; kk < 8; ++kk)
            a[kk] = *(const v8h*)(ab + 32 * kk);
        #pragma unroll
        for (int tt = 0; tt < 4; ++tt) {
            v4f Ca = {0.f,0.f,0.f,0.f}, Cb = {0.f,0.f,0.f,0.f};
            #pragma unroll
            for (int kk = 0; kk < 8; kk += 2) {
                v8h f0 = *(const v8h*)(wt + (cb + tt) * 256 + 32 * kk + kq);
                v8h f1 = *(const v8h*)(wt + (cb + tt) * 256 + 32 * (kk + 1) + kq);
                Ca = __builtin_amdgcn_mfma_f32_16x16x32_f16(a[kk], f0, Ca, 0, 0, 0);
                Cb = __builtin_amdgcn_mfma_f32_16x16x32_f16(a[kk + 1], f1, Cb, 0, 0, 0);
            }
            v4f Cs = Ca + Cb;
            z1[tt] = Cs[0] + b1r[tt];
            P[tt]  = Cs[1];
        }
    }
    __syncthreads();   // prologue reads done before u(0) overwrites buf0

    const float dt = 0.01f, hdt = 0.005f, dt6 = 0.01f / 6.f;
    const float dtdt6 = dt * dt6, hdt2 = hdt * hdt, dthdt = dt * hdt;
    const float fourdt = 4.f * dt;
    // per-quad (step j = quad) predictor coefs (R27-verified)
    const float qf  = (float)quad;
    const float cPn   = -(qf * 0.25f * dt6);
    const float K2cz1 = 2.f * qf * dt;
    const float K2B   = qf * (4.f - qf) * dtdt6 * 0.25f;
    const float K2Vn  = -(qf * dtdt6 * 0.5f);
    const float K2hdt = 2.f * hdt;
    const float K2hdt2n = -2.f * hdt2;
    const float K2dt  = 2.f * dt;
    const float K2dthdtn = -2.f * dthdt;
    const float wB  = 3.f - qf;

    // ---- main-loop LDS addressing (swizzle derivations in header) ----
    const int bsw = (s >> 2) & 1;
    const int rdbase = s * 256 + 8 * (quad ^ (s & 3));
    const _Float16* pe = ubuf + rdbase + 32 * bsw;         // logical even kk
    const _Float16* po = ubuf + rdbase + 32 * (1 - bsw);   // logical odd  kk
    const int R0 = 4 * quad;
    const int wo0 = (R0 + 0) * 256 + 8 * (chb ^ ((R0 + 0) & 7)) + clo;
    const int wo1 = (R0 + 1) * 256 + 8 * (chb ^ ((R0 + 1) & 7)) + clo;
    const int wo2 = (R0 + 2) * 256 + 8 * (chb ^ ((R0 + 2) & 7)) + clo;
    const int wo3 = (R0 + 3) * 256 + 8 * (chb ^ ((R0 + 3) & 7)) + clo;

    // lag state (exchange 0: zeros -> benign one-time transient)
    float SBp[4] = {0.f,0.f,0.f,0.f}, SVp[4] = {0.f,0.f,0.f,0.f};
    float Y1L[4] = {0.f,0.f,0.f,0.f}, Y2L[4] = {0.f,0.f,0.f,0.f};
    float S1p[4] = {0.f,0.f,0.f,0.f}, S23p[4] = {0.f,0.f,0.f,0.f};
    float cn = 99.f - qf;

    #pragma unroll 1
    for (int e = 0; e < NEX; ++e) {
        const int bo = (e & 1) * 4096;   // double-buffer offset (f16 units)

        // ---- predictor + 16 u-evals (4 comps x 4 stages) ----
        float ua[4], ub[4], uc[4], ud[4];
        #pragma unroll
        for (int tt = 0; tt < 4; ++tt) {
            float Pp  = __builtin_fmaf(cPn, SBp[tt], P[tt]);
            float zp2 = __builtin_fmaf(K2cz1, P[tt], z1[tt] + z1[tt]);
            zp2 = __builtin_fmaf(K2B, SBp[tt], zp2);
            zp2 = __builtin_fmaf(K2Vn, SVp[tt], zp2);
            float zb2 = __builtin_fmaf(K2hdt, Pp, zp2);
            float zc2 = __builtin_fmaf(K2hdt2n, Y1L[tt], zb2);
            float zd2 = __builtin_fmaf(K2dt, Pp, zp2);
            zd2 = __builtin_fmaf(K2dthdtn, Y2L[tt], zd2);
            ua[tt] = ueval2(zp2, w4v[tt]);
            ub[tt] = ueval2(zb2, w4v[tt]);
            uc[tt] = ueval2(zc2, w4v[tt]);
            ud[tt] = ueval2(zd2, w4v[tt]);
        }

        // ---- pack 4 comps/row -> 4 x ds_write_b64 ----
        {
            v4h ra = {(_Float16)ua[0], (_Float16)ua[1], (_Float16)ua[2], (_Float16)ua[3]};
            v4h rb = {(_Float16)ub[0], (_Float16)ub[1], (_Float16)ub[2], (_Float16)ub[3]};
            v4h rc = {(_Float16)uc[0], (_Float16)uc[1], (_Float16)uc[2], (_Float16)uc[3]};
            v4h rd = {(_Float16)ud[0], (_Float16)ud[1], (_Float16)ud[2], (_Float16)ud[3]};
            *(v4h*)(ubuf + bo + wo0) = ra;
            *(v4h*)(ubuf + bo + wo1) = rb;
            *(v4h*)(ubuf + bo + wo2) = rc;
            *(v4h*)(ubuf + bo + wo3) = rd;
        }
        __syncthreads();   // the ONLY barrier per exchange (4 waves)

        // ---- 8 A-frags once; 4 tiles x 8 MFMA (A reused) ----
        v8h a0 = *(const v8h*)(pe + bo);
        v8h a1 = *(const v8h*)(po + bo);
        v8h a2 = *(const v8h*)(pe + bo + 64);
        v8h a3 = *(const v8h*)(po + bo + 64);
        v8h a4 = *(const v8h*)(pe + bo + 128);
        v8h a5 = *(const v8h*)(po + bo + 128);
        v8h a6 = *(const v8h*)(pe + bo + 192);
        v8h a7 = *(const v8h*)(po + bo + 192);
        v4f Ca[4], Cb[4];
        #pragma unroll
        for (int tt = 0; tt < 4; ++tt) {
            Ca[tt] = (v4f){0.f,0.f,0.f,0.f};
            Cb[tt] = (v4f){0.f,0.f,0.f,0.f};
            MFMA_AV(Ca[tt], a0, wM[tt][0]);
            MFMA_AV(Cb[tt], a1, wM[tt][1]);
            MFMA_AV(Ca[tt], a2, wM[tt][2]);
            MFMA_AV(Cb[tt], a3, wM[tt][3]);
            MFMA_AV(Ca[tt], a4, wM[tt][4]);
            MFMA_AV(Cb[tt], a5, wM[tt][5]);
            MFMA_AV(Ca[tt], a6, wM[tt][6]);
            MFMA_AV(Cb[tt], a7, wM[tt][7]);
        }
        // no second barrier: next exchange writes the OTHER buffer (R24).

        // ---- S partials in the MFMA shadow (uses pre-barrier u's) ----
        #pragma unroll
        for (int tt = 0; tt < 4; ++tt) {
            float tv = ub[tt] + uc[tt];
            float sp = __builtin_fmaf(2.f, tv, ua[tt] + ud[tt]);
            float sq = ua[tt] + tv;
            S1p[tt] += sp;
            S23p[tt] = __builtin_fmaf(cn, sp, S23p[tt]) + sq;
        }
        cn -= 4.f;

        // ---- combos, 2 bfly per comp, EXACT 4-step advance ----
        #pragma unroll
        for (int tt = 0; tt < 4; ++tt) {
            v4f Cs = Ca[tt] + Cb[tt];
            float Y1 = Cs[0], Y2 = Cs[1], Y3 = Cs[2], Y4 = Cs[3];
            float tA = Y2 + Y3;
            float A  = Y1 + tA;                    // Y1+Y2+Y3
            float B  = A + tA + Y4;                // Y1+2Y2+2Y3+Y4
            float V  = __builtin_fmaf(wB, B, A);   // (3-j)*B + A
            float SB = bfly4(B);
            float SV = bfly4(V);                   // = SWB + SA (exact)
            z1[tt] = __builtin_fmaf(fourdt, P[tt], z1[tt]);
            z1[tt] = __builtin_fmaf(-dtdt6, SV, z1[tt]);
            P[tt]  = __builtin_fmaf(-dt6, SB, P[tt]);
            SBp[tt] = SB;  SVp[tt] = SV;  Y1L[tt] = Y1;  Y2L[tt] = Y2;
        }
    }

    // ---- epilogue: reduce S; rows {S1, S23, 0, 0}; final MFMA ----
    float S1f[4], S23f[4];
    #pragma unroll
    for (int tt = 0; tt < 4; ++tt) {
        S1f[tt]  = bfly4(S1p[tt]);
        S23f[tt] = bfly4(S23p[tt]);
    }
    __syncthreads();   // last exchange's reads (buf0, e=24) done
    if (quad == 0) {
        v4h r0 = {(_Float16)S1f[0], (_Float16)S1f[1],
                  (_Float16)S1f[2], (_Float16)S1f[3]};
        v4h r1 = {(_Float16)S23f[0], (_Float16)S23f[1],
                  (_Float16)S23f[2], (_Float16)S23f[3]};
        v4h rz = {(_Float16)0.f, (_Float16)0.f, (_Float16)0.f, (_Float16)0.f};
        *(v4h*)(ubuf + 0 * 256 + 8 * (chb ^ 0) + clo) = r0;
        *(v4h*)(ubuf + 1 * 256 + 8 * (chb ^ 1) + clo) = r1;
        *(v4h*)(ubuf + 2 * 256 + 8 * (chb ^ 2) + clo) = rz;
        *(v4h*)(ubuf + 3 * 256 + 8 * (chb ^ 3) + clo) = rz;
    }
    __syncthreads();
    float D1[4], D2[4];
    {
        const _Float16* ab = ubuf + (s & 3) * 256 + 8 * (quad ^ (s & 3));
        v8h a[8];
        #pragma unroll
        for (int kk = 0; kk < 8; ++kk)
            a[kk] = *(const v8h*)(ab + 32 * kk);
        #pragma unroll
        for (int tt = 0; tt < 4; ++tt) {
            v4f Ca = {0.f,0.f,0.f,0.f}, Cb = {0.f,0.f,0.f,0.f};
            #pragma unroll
            for (int kk = 0; kk < 8; ++kk) {
                // wBt from GLOBAL W1 (contiguous; same f32->f16 as setup)
                const float* wp = W1 + (cb + tt) * 256 + 32 * kk + kq;
                v4f lo = *(const v4f*)(wp);
                v4f hi = *(const v4f*)(wp + 4);
                v8h h;
                h[0] = (_Float16)lo[0]; h[1] = (_Float16)lo[1];
                h[2] = (_Float16)lo[2]; h[3] = (_Float16)lo[3];
                h[4] = (_Float16)hi[0]; h[5] = (_Float16)hi[1];
                h[6] = (_Float16)hi[2]; h[7] = (_Float16)hi[3];
                if (kk & 1)
                    Cb = __builtin_amdgcn_mfma_f32_16x16x32_f16(a[kk], h, Cb, 0, 0, 0);
                else
                    Ca = __builtin_amdgcn_mfma_f32_16x16x32_f16(a[kk], h, Ca, 0, 0, 0);
            }
            v4f Cs = Ca + Cb;
            D1[tt] = Cs[0];  D2[tt] = Cs[1];
        }
    }
    const float dt6e = 0.01f / 6.f, dtdt6e = 0.01f * dt6e;
    if (quad == 0) {
        float pT[4], qT[4];
        #pragma unroll
        for (int tt = 0; tt < 4; ++tt) {
            pT[tt] = p0v[tt] - dt6e * D1[tt];
            qT[tt] = q0v[tt] + 0.01f * 100.f * p0v[tt] - dtdt6e * D2[tt];
        }
        v4f o01 = {qT[0], pT[0], qT[1], pT[1]};
        v4f o23 = {qT[2], pT[2], qT[3], pT[3]};
        *(v4f*)(out + (size_t)blk * 512 + 2 * cb) = o01;
        *(v4f*)(out + (size_t)blk * 512 + 2 * cb + 4) = o23;
    }
}

extern "C" void kernel_launch(void* const* d_in, const int* in_sizes, int n_in,
                              void* d_out, int out_size, void* d_ws, size_t ws_size,
                              hipStream_t stream) {
    const float* x0 = (const float*)d_in[0];
    const float* W1 = (const float*)d_in[1];
    const float* b1 = (const float*)d_in[2];
    const float* W2 = (const float*)d_in[3];
    // d_in[4] = b2: constant offset, no effect on the gradient/dynamics.
    float* out = (float*)d_out;
    // workspace: Wt_f16 [256*256] then Mf16 [256*256]  (262144 B total)
    _Float16* wt = (_Float16*)d_ws;
    _Float16* mf = wt + 256 * 256;
    hipLaunchKernelGGL(ham_setup, dim3(256), dim3(256), 0, stream, W1, wt, mf);
    hipLaunchKernelGGL(ham_kernel, dim3(256), dim3(256), 0, stream,
                       x0, W1, b1, W2, wt, mf, out);
}

// Round 11
// 92.884 us; speedup vs baseline: 1.1835x; 1.1549x over previous
//
#include <hip/hip_runtime.h>
#include <stdint.h>

// HamiltonianFlow: x [256, 8, 32, 2] (q,p); H = 0.5*sum(p^2) + MLP(q).
// dq/dt = p, dp/dt = -W u(z), z = W^T q + b1, u = (1-tanh^2(z)).*W2.
// z-space iteration with M = W^T W (R15-R23 verified).
//
// R33 = R30 + COMBO-LINEARITY: 8 steps per 16-row A-tile, 13 exchanges.
// R32 (5th structure at ~44us, busy metrics DOWN, time flat) proved the
// wall is one system's serial chain: ~4.2k cyc/exchange of sync+latency
// tax, structure-invariant. Only lever: fewer exchanges. Key algebra:
// the advance/predictor need only A_j = Y1+Y2+Y3, B_j = Y1+2Y2+2Y3+Y4,
// and Y_i = M u_i  =>  sum u's BEFORE the matvec:
//   row(2j)   = uA_j = ua+ub+uc
//   row(2j+1) = uB_j = ua+2ub+2uc+ud
// 16 rows = 8 steps; SAME tile/MFMA/write/read/swizzle as R30, HALF the
// exchanges (12 full + 4-step tail). Stage-lag Y1L/Y2L (no longer
// separable) ~ A_prev/3 (Y_i differ by O(dt): correction err ~5e-7,
// 3 orders under f16 floor). 8-step advance + horizon-8 predictor =
// R29b/R29c-verified formulas (bit-identical absmax there):
//   z += 8dt*P - dtdt6*SV8;  P -= dt6*SB8
//   SB8 = sum B_j;  SV8 = sum (7-j)B_j + sum A_j
//   pred step j: Pp = P - (j/8)dt6*SBp;
//     zp2 = 2z + 2j*dt*P + dtdt6*j(8-j)/8*SBp - dtdt6*(j/4)*SVp
// Lane (quad q) owns steps j1=2q, j2=2q+1 (C rows 4q..4q+3 =
// {A_j1,B_j1,A_j2,B_j2} in-lane); V-partial = (7-j1)B1+(7-j2)B2+A1+A2
// = fma(7-j1, B1+B2, A1+A2-B2); 2 bfly4 per 8 steps. S-identity:
// sp=uB, sq=uA (pre-f16) -> S1p += uB1+uB2; S23p += cn*uB+uA terms.
// Combos f16-rounded once post-sum (same class as summing f16 terms).
// Tail (steps 96-99): quads 0,1 valid (j<4), quads 2,3 write zero
// combos; H=4 weights (3-j); advance z += 4dt*P - dtdt6*SV4.
// Race safety: R24 double-buffer argument; tail's buf0 write is after
// barrier(e=11) which implies all e=10 buf0-reads completed.
//
// R30 substrate (best measured, 46.8us): 16 waves x 1 tile (1024 thr),
// in-kernel W^T staging + M-build, ONE barrier per exchange, R30
// bank-swizzle (rows: ^((row>>2)&3)<<3 chunk XOR + odd-row ^32),
// permlane bfly4, exp-fold (2z chain) + rcp, mscr UNION ubuf.
// FULL unroll on every reg-array access (R4: dynamic index => scratch).
// Numerics: f16 storage (W, M, uA/uB, S), fp32 MFMA accum + fp32 z/P.

typedef _Float16 v8h __attribute__((ext_vector_type(8)));
typedef float v4f __attribute__((ext_vector_type(4)));

#define NFULL 12  // full 8-step exchanges; + 1 tail exchange of 4 steps
#define WS 264    // wldsT row stride (f16): row = one W-COLUMN, 16B-aligned
#define US 272    // ubuf row stride, f16 (544 B == 32 mod 128)

// D(+=C) in VGPRs, A (packed-vector frag) in VGPRs, B (M-frag) from AGPRs.
#define MFMA_AV(C, A, B) \
    asm("v_mfma_f32_16x16x32_f16 %0, %1, %2, %0" : "+v"(C) : "v"(A), "a"(B))

// 4-group butterfly sum over lanes {l, l^16, l^32, l^48}, pure VALU.
__device__ __forceinline__ float bfly4(float x) {
    float a = x, b = x;
    asm("v_permlane16_swap_b32 %0, %1" : "+v"(a), "+v"(b));
    float s = a + b;
    float c = s, d = s;
    asm("v_permlane32_swap_b32 %0, %1" : "+v"(c), "+v"(d));
    return c + d;
}

// u/(4*w2) eval on pre-doubled arg zz = 2*z:  r = rcp(e^zz + 1);
// u = 4*w2*(r - r^2)  ==  (1 - tanh^2(z)) * w2  exactly in algebra.
__device__ __forceinline__ float ueval2(float zz, float w4) {
    float e_ = __expf(zz);
    float r_ = __builtin_amdgcn_rcpf(e_ + 1.f);   // vs IEEE div: ~1e-7 rel
    return w4 * __builtin_fmaf(-r_, r_, r_);
}

__global__ __launch_bounds__(1024, 4)
void ham_kernel(const float* __restrict__ x0, const float* __restrict__ W1,
                const float* __restrict__ b1, const float* __restrict__ W2,
                float* __restrict__ out)
{
    __shared__ __align__(16)  _Float16 wldsT[256 * WS];  // 135168 B: W^T (f16)
    __shared__ __align__(128) char     upool[20480];     // mscr UNION ubuf
    float*    mscr = (float*)upool;                      // setup only
    _Float16* ubuf = (_Float16*)upool;                   // 2 x 16 rows x US

    const int t = threadIdx.x;
    const int w = t >> 6;          // wave 0..15: owns tile w (16 comps)
    const int l = t & 63;
    const int quad = l >> 4;       // owns steps 2*quad, 2*quad+1
    const int s = l & 15;          // owned column / A-row
    const int c0 = 16 * w + s;     // owned component
    const int blk = blockIdx.x;
    const int sel = (s & 3) * US;  // prologue/epilogue A-row select (rows 0-3)

    // ---- stage W^T -> LDS f16: wldsT[c][r] = W[r][c] ----
    {
        const int c = t & 255;
        const int rbase = (t >> 8) * 64;   // 4 quarters x 64 rows
        #pragma unroll 1
        for (int r0 = 0; r0 < 64; r0 += 8) {
            v8h h;
            #pragma unroll
            for (int j = 0; j < 8; ++j)
                h[j] = (_Float16)W1[(rbase + r0 + j) * 256 + c];
            *(v8h*)(wldsT + c * WS + rbase + r0) = h;   // b128, one-time
        }
    }
    __syncthreads();

    // ---- wF: own-column W^T frag (B-op), contiguous b128 from wldsT ----
    v8h wF0[8];
    #pragma unroll
    for (int kk = 0; kk < 8; ++kk)
        wF0[kk] = *(const v8h*)(wldsT + c0 * WS + 32 * kk + 8 * quad);

    // ---- build M = W^T W column-block frags wM0 (B-op: M[k][c0]) ----
    v8h wM0[8];
    float* scr0 = mscr + w * 320;
    #pragma unroll
    for (int kb = 0; kb < 16; ++kb) {
        v8h aM[8];   // A[m=s][k=8quad+j] = wldsT[(16kb+s)*WS + 32kk+8quad+j]
        #pragma unroll
        for (int kk = 0; kk < 8; ++kk)
            aM[kk] = *(const v8h*)(wldsT + (16 * kb + s) * WS
                                          + 32 * kk + 8 * quad);
        v4f D0 = {0.f,0.f,0.f,0.f};
        #pragma unroll
        for (int kk = 0; kk < 8; ++kk)
            D0 = __builtin_amdgcn_mfma_f32_16x16x32_f16(aM[kk], wF0[kk], D0, 0, 0, 0);
        *(v4f*)(scr0 + s * 20 + 4 * quad) = D0;
        asm volatile("s_waitcnt lgkmcnt(0)" ::: "memory");  // in-wave x-lane
        if ((quad >> 1) == (kb & 1)) {
            #pragma unroll
            for (int j = 0; j < 8; ++j)
                wM0[kb >> 1][j] = (_Float16)scr0[s * 20 + 8 * (quad & 1) + j];
        }
        asm volatile("s_waitcnt lgkmcnt(0)" ::: "memory");
    }
    __syncthreads();   // mscr reads (all waves) done before ubuf reuse

    const float b1r0 = b1[c0];
    const float w4 = 4.f * W2[c0];
    float2 qp0 = ((const float2*)(x0 + (size_t)blk * 512))[c0];
    const float q0o0 = qp0.x, p0o0 = qp0.y;

    // ---- prologue: buf0 rows {q0, p0, 0, 0} -> z1 (C[0]), P (C[1]) ----
    if (quad == 0) {
        ubuf[c0] = (_Float16)q0o0;
        ubuf[US + c0] = (_Float16)p0o0;
        ubuf[2 * US + c0] = (_Float16)0.f;
        ubuf[3 * US + c0] = (_Float16)0.f;
    }
    __syncthreads();
    float z1, P;
    {
        const _Float16* ab = ubuf + sel + 8 * quad;
        v4f C0a = {0.f,0.f,0.f,0.f}, C0b = {0.f,0.f,0.f,0.f};
        #pragma unroll
        for (int kk = 0; kk < 8; kk += 2) {
            v8h a0 = *(const v8h*)(ab + 32 * kk);
            v8h a1 = *(const v8h*)(ab + 32 * (kk + 1));
            C0a = __builtin_amdgcn_mfma_f32_16x16x32_f16(a0, wF0[kk], C0a, 0, 0, 0);
            C0b = __builtin_amdgcn_mfma_f32_16x16x32_f16(a1, wF0[kk + 1], C0b, 0, 0, 0);
        }
        v4f C0s = C0a + C0b;
        z1 = C0s[0] + b1r0;  P = C0s[1];
    }
    __syncthreads();   // prologue reads done before u(0) overwrites buf0

    const float dt = 0.01f, hdt = 0.005f, dt6 = 0.01f / 6.f;
    const float dtdt6 = dt * dt6, hdt2 = hdt * hdt, dthdt = dt * hdt;
    const float K8dt = 8.f * dt, K4dt = 4.f * dt;
    // steps j1 = 2q, j2 = 2q+1; horizon-8 predictor coefs (R29c-verified)
    const float j1 = 2.f * (float)quad, j2 = j1 + 1.f;
    const float cPn1 = -(j1 * 0.125f * dt6), cPn2 = -(j2 * 0.125f * dt6);
    const float Kz1a = 2.f * j1 * dt,        Kz1b = 2.f * j2 * dt;
    const float KB1 = dtdt6 * j1 * (8.f - j1) * 0.125f;
    const float KB2 = dtdt6 * j2 * (8.f - j2) * 0.125f;
    const float KVn1 = -(j1 * dtdt6 * 0.25f), KVn2 = -(j2 * dtdt6 * 0.25f);
    const float K2hdt = 2.f * hdt;
    const float K2dt  = 2.f * dt;
    const float KC1n = -(2.f * hdt2) / 3.f;   // zc: -2hdt^2 * (A/3) folded
    const float KC2n = -(2.f * dthdt) / 3.f;  // zd: -2*dt*hdt * (A/3) folded
    const float w71 = 7.f - j1;               // V = fma(w71, B1+B2, A1+A2-B2)
    const float w31 = 3.f - j1;               // tail H=4 V weight

    // ---- ubuf addressing (R30 bank swizzle, measured-neutral, kept) ----
    const int cw = c0 ^ (quad << 3);
    const int R0 = 4 * quad;
    const int wo0 = (R0 + 0) * US + cw;          // row 4q   = uA(j1)
    const int wo1 = (R0 + 1) * US + (cw ^ 32);   // row 4q+1 = uB(j1)
    const int wo2 = (R0 + 2) * US + cw;          // row 4q+2 = uA(j2)
    const int wo3 = (R0 + 3) * US + (cw ^ 32);   // row 4q+3 = uB(j2)
    const int sx = (s >> 2) & 3;
    const int rbase = s * US + 8 * (quad ^ sx);
    const int sodd = (s & 1) << 5;
    const _Float16* pe = ubuf + rbase + sodd;          // logical even kk
    const _Float16* po = ubuf + rbase + 32 - sodd;     // logical odd  kk

    // lag state (exchange 0: zeros -> benign one-time transient)
    float SBp = 0.f, SVp = 0.f;
    float AL1 = 0.f, AL2 = 0.f;    // own-step A-combo lags (Y1~Y2~A/3)
    float S1p = 0.f, S23p = 0.f;
    float cn1 = 99.f - j1;         // step n1 = 8e + j1; n2 = n1 + 1

    #pragma unroll 1
    for (int e = 0; e < NFULL; ++e) {
        const int bo = (e & 1) * (16 * US);   // double-buffer offset

        // ---- predict both steps; 8 stage-z's; 8 u evals; 4 combos ----
        float z1d = z1 + z1;
        float Pp1  = __builtin_fmaf(cPn1, SBp, P);
        float zp21 = __builtin_fmaf(Kz1a, P, z1d);
        zp21 = __builtin_fmaf(KB1, SBp, zp21);
        zp21 = __builtin_fmaf(KVn1, SVp, zp21);
        float zb21 = __builtin_fmaf(K2hdt, Pp1, zp21);
        float zc21 = __builtin_fmaf(KC1n, AL1, zb21);
        float zd21 = __builtin_fmaf(K2dt, Pp1, zp21);
        zd21 = __builtin_fmaf(KC2n, AL1, zd21);
        float Pp2  = __builtin_fmaf(cPn2, SBp, P);
        float zp22 = __builtin_fmaf(Kz1b, P, z1d);
        zp22 = __builtin_fmaf(KB2, SBp, zp22);
        zp22 = __builtin_fmaf(KVn2, SVp, zp22);
        float zb22 = __builtin_fmaf(K2hdt, Pp2, zp22);
        float zc22 = __builtin_fmaf(KC1n, AL2, zb22);
        float zd22 = __builtin_fmaf(K2dt, Pp2, zp22);
        zd22 = __builtin_fmaf(KC2n, AL2, zd22);

        float ua1 = ueval2(zp21, w4), ub1 = ueval2(zb21, w4);
        float uc1 = ueval2(zc21, w4), ud1 = ueval2(zd21, w4);
        float ua2 = ueval2(zp22, w4), ub2 = ueval2(zb22, w4);
        float uc2 = ueval2(zc22, w4), ud2 = ueval2(zd22, w4);

        float tv1 = ub1 + uc1;
        float uA1 = ua1 + tv1;                                // = sq(j1)
        float uB1 = __builtin_fmaf(2.f, tv1, ua1 + ud1);      // = sp(j1)
        float tv2 = ub2 + uc2;
        float uA2 = ua2 + tv2;
        float uB2 = __builtin_fmaf(2.f, tv2, ua2 + ud2);

        ubuf[bo + wo0] = (_Float16)uA1;
        ubuf[bo + wo1] = (_Float16)uB1;
        ubuf[bo + wo2] = (_Float16)uA2;
        ubuf[bo + wo3] = (_Float16)uB2;
        __syncthreads();   // the ONLY barrier per exchange (8 steps)

        // ---- ONE MFMA block: {A1,B1,A2,B2} combos for own comp ----
        v4f C0s;
        {
            v4f C0a = {0.f,0.f,0.f,0.f}, C0b = {0.f,0.f,0.f,0.f};
            #pragma unroll
            for (int kk = 0; kk < 8; kk += 2) {
                v8h a0 = *(const v8h*)(pe + bo + 32 * kk);
                v8h a1 = *(const v8h*)(po + bo + 32 * kk);
                MFMA_AV(C0a, a0, wM0[kk]);
                MFMA_AV(C0b, a1, wM0[kk + 1]);
            }
            C0s = C0a + C0b;
        }
        // no second barrier: next exchange writes the OTHER buffer (R24).

        // ---- EXACT 8-step advance via 2 butterflies ----
        float A1 = C0s[0], B1 = C0s[1], A2 = C0s[2], B2 = C0s[3];
        float Bs = B1 + B2;
        float V  = __builtin_fmaf(w71, Bs, A1 + A2 - B2);  // (7-j1)B1+(7-j2)B2+A1+A2
        float SB = bfly4(Bs);
        float SV = bfly4(V);

        z1 = __builtin_fmaf(K8dt, P, z1);      // z += 8dt*P (old P)
        z1 = __builtin_fmaf(-dtdt6, SV, z1);
        P  = __builtin_fmaf(-dt6, SB, P);

        SBp = SB;  SVp = SV;  AL1 = A1;  AL2 = A2;   // lag state

        // ---- S partials (identities sp=uB, sq=uA, pre-f16 f32) ----
        S1p += uB1 + uB2;
        S23p = __builtin_fmaf(cn1, uB1, S23p) + uA1;
        S23p = __builtin_fmaf(cn1 - 1.f, uB2, S23p) + uA2;
        cn1 -= 8.f;
    }

    // ---- tail exchange: steps 96-99, buf0 (safe: post-barrier(e=11)),
    //      quads 0,1 valid (j1<4), quads 2,3 zero combos; H=4 exact ----
    {
        const float vm = (quad < 2) ? 1.f : 0.f;
        float z1d = z1 + z1;
        float Pp1  = __builtin_fmaf(cPn1, SBp, P);
        float zp21 = __builtin_fmaf(Kz1a, P, z1d);
        zp21 = __builtin_fmaf(KB1, SBp, zp21);
        zp21 = __builtin_fmaf(KVn1, SVp, zp21);
        float zb21 = __builtin_fmaf(K2hdt, Pp1, zp21);
        float zc21 = __builtin_fmaf(KC1n, AL1, zb21);
        float zd21 = __builtin_fmaf(K2dt, Pp1, zp21);
        zd21 = __builtin_fmaf(KC2n, AL1, zd21);
        float Pp2  = __builtin_fmaf(cPn2, SBp, P);
        float zp22 = __builtin_fmaf(Kz1b, P, z1d);
        zp22 = __builtin_fmaf(KB2, SBp, zp22);
        zp22 = __builtin_fmaf(KVn2, SVp, zp22);
        float zb22 = __builtin_fmaf(K2hdt, Pp2, zp22);
        float zc22 = __builtin_fmaf(KC1n, AL2, zb22);
        float zd22 = __builtin_fmaf(K2dt, Pp2, zp22);
        zd22 = __builtin_fmaf(KC2n, AL2, zd22);

        float ua1 = ueval2(zp21, w4), ub1 = ueval2(zb21, w4);
        float uc1 = ueval2(zc21, w4), ud1 = ueval2(zd21, w4);
        float ua2 = ueval2(zp22, w4), ub2 = ueval2(zb22, w4);
        float uc2 = ueval2(zc22, w4), ud2 = ueval2(zd22, w4);

        float tv1 = ub1 + uc1;
        float uA1 = (ua1 + tv1) * vm;
        float uB1 = __builtin_fmaf(2.f, tv1, ua1 + ud1) * vm;
        float tv2 = ub2 + uc2;
        float uA2 = (ua2 + tv2) * vm;
        float uB2 = __builtin_fmaf(2.f, tv2, ua2 + ud2) * vm;

        ubuf[wo0] = (_Float16)uA1;
        ubuf[wo1] = (_Float16)uB1;
        ubuf[wo2] = (_Float16)uA2;
        ubuf[wo3] = (_Float16)uB2;
        __syncthreads();

        v4f C0s;
        {
            v4f C0a = {0.f,0.f,0.f,0.f}, C0b = {0.f,0.f,0.f,0.f};
            #pragma unroll
            for (int kk = 0; kk < 8; kk += 2) {
                v8h a0 = *(const v8h*)(pe + 32 * kk);
                v8h a1 = *(const v8h*)(po + 32 * kk);
                MFMA_AV(C0a, a0, wM0[kk]);
                MFMA_AV(C0b, a1, wM0[kk + 1]);
            }
            C0s = C0a + C0b;
        }
        float A1 = C0s[0], B1 = C0s[1], A2 = C0s[2], B2 = C0s[3];
        float Bs = B1 + B2;
        float V  = __builtin_fmaf(w31, Bs, A1 + A2 - B2);  // (3-j1)B1+(3-j2)B2+A1+A2
        float SB = bfly4(Bs);
        float SV = bfly4(V);
        z1 = __builtin_fmaf(K4dt, P, z1);
        z1 = __builtin_fmaf(-dtdt6, SV, z1);
        P  = __builtin_fmaf(-dt6, SB, P);
        S1p += uB1 + uB2;                       // cn1 = 3-j1 here (checked)
        S23p = __builtin_fmaf(cn1, uB1, S23p) + uA1;
        S23p = __builtin_fmaf(cn1 - 1.f, uB2, S23p) + uA2;
    }

    // ---- epilogue: reduce S over quads; buf0 rows {S1, S23, 0, 0} ----
    const float S1f  = bfly4(S1p);
    const float S23f = bfly4(S23p);
    __syncthreads();   // tail's buf0 reads done before overwrite
    if (quad == 0) {
        ubuf[c0] = (_Float16)S1f;
        ubuf[US + c0] = (_Float16)S23f;
        ubuf[2 * US + c0] = (_Float16)0.f;
        ubuf[3 * US + c0] = (_Float16)0.f;
    }
    __syncthreads();
    // wBt[kk][j] = W[c0][32kk+8quad+j] = wldsT[(32kk+8quad+j)*WS + c0]
    v8h wBt0[8];
    #pragma unroll
    for (int kk = 0; kk < 8; ++kk)
        #pragma unroll
        for (int j = 0; j < 8; ++j)
            wBt0[kk][j] = wldsT[(32 * kk + 8 * quad + j) * WS + c0];
    float D10, D20;
    {
        const _Float16* ab = ubuf + sel + 8 * quad;
        v4f C0a = {0.f,0.f,0.f,0.f}, C0b = {0.f,0.f,0.f,0.f};
        #pragma unroll
        for (int kk = 0; kk < 8; kk += 2) {
            v8h a0 = *(const v8h*)(ab + 32 * kk);
            v8h a1 = *(const v8h*)(ab + 32 * (kk + 1));
            C0a = __builtin_amdgcn_mfma_f32_16x16x32_f16(a0, wBt0[kk], C0a, 0, 0, 0);
            C0b = __builtin_amdgcn_mfma_f32_16x16x32_f16(a1, wBt0[kk + 1], C0b, 0, 0, 0);
        }
        v4f C0s = C0a + C0b;
        D10 = C0s[0];  D20 = C0s[1];
    }
    const float dt6e = 0.01f / 6.f, dtdt6e = 0.01f * dt6e;
    float pT0 = p0o0 - dt6e * D10;
    float qT0 = q0o0 + 0.01f * 100.f * p0o0 - dtdt6e * D20;

    if (quad == 0)
        ((float2*)(out + (size_t)blk * 512))[c0] = make_float2(qT0, pT0);
}

extern "C" void kernel_launch(void* const* d_in, const int* in_sizes, int n_in,
                              void* d_out, int out_size, void* d_ws, size_t ws_size,
                              hipStream_t stream) {
    const float* x0 = (const float*)d_in[0];
    const float* W1 = (const float*)d_in[1];
    const float* b1 = (const float*)d_in[2];
    const float* W2 = (const float*)d_in[3];
    // d_in[4] = b2: constant offset, no effect on the gradient/dynamics.
    float* out = (float*)d_out;
    hipLaunchKernelGGL(ham_kernel, dim3(256), dim3(1024), 0, stream,
                       x0, W1, b1, W2, out);
}